// Round 6
// baseline (1179.713 us; speedup 1.0000x reference)
//
#include <hip/hip_runtime.h>
#include <stdint.h>

#define USER_COUNT 100000
#define ITEM_COUNT 50000
#define N_NODES    150000
#define EMB        64
#define N_EDGES    4000000
#define BATCH      4096
#define EPS_F      0.2f
#define NB_SCAN    ((N_NODES + 255) / 256)   // 586

typedef int int4v __attribute__((ext_vector_type(4)));

// ---- JAX threefry-2x32 (20 rounds), bit-exact ----
__host__ __device__ inline void threefry2x32(uint32_t k0, uint32_t k1,
                                             uint32_t& x0, uint32_t& x1) {
  const uint32_t ks2 = k0 ^ k1 ^ 0x1BD11BDAu;
  x0 += k0; x1 += k1;
#define TF_ROT(r) { x0 += x1; x1 = (x1 << (r)) | (x1 >> (32 - (r))); x1 ^= x0; }
  TF_ROT(13) TF_ROT(15) TF_ROT(26) TF_ROT(6)
  x0 += k1;  x1 += ks2 + 1u;
  TF_ROT(17) TF_ROT(29) TF_ROT(16) TF_ROT(24)
  x0 += ks2; x1 += k0 + 2u;
  TF_ROT(13) TF_ROT(15) TF_ROT(26) TF_ROT(6)
  x0 += k0;  x1 += k1 + 3u;
  TF_ROT(17) TF_ROT(29) TF_ROT(16) TF_ROT(24)
  x0 += k1;  x1 += ks2 + 4u;
  TF_ROT(13) TF_ROT(15) TF_ROT(26) TF_ROT(6)
  x0 += ks2; x1 += k0 + 5u;
#undef TF_ROT
}

__global__ void k_zero(int* __restrict__ p, int n) {
  int i = blockIdx.x * blockDim.x + threadIdx.x;
  if (i < n) p[i] = 0;
}

__global__ void k_hist(const int* __restrict__ rows, int* __restrict__ deg) {
  const int4v* __restrict__ r4 = (const int4v*)rows;
  int stride = gridDim.x * blockDim.x;
  for (int e = blockIdx.x * blockDim.x + threadIdx.x; e < N_EDGES / 4; e += stride) {
    int4v r = __builtin_nontemporal_load(r4 + e);
    atomicAdd(&deg[r.x], 1); atomicAdd(&deg[r.y], 1);
    atomicAdd(&deg[r.z], 1); atomicAdd(&deg[r.w], 1);
  }
}

// ---- parallel scan over deg: bsum -> bscan -> finalize ----
__global__ void k_bsum(const int* __restrict__ deg, int* __restrict__ bsum) {
  const int i = blockIdx.x * 256 + threadIdx.x;
  const int lane = threadIdx.x & 63, wid = threadIdx.x >> 6;
  int d = (i < N_NODES) ? deg[i] : 0;
#pragma unroll
  for (int s = 32; s; s >>= 1) d += __shfl_down(d, s);
  __shared__ int ws[4];
  if (lane == 0) ws[wid] = d;
  __syncthreads();
  if (threadIdx.x == 0) bsum[blockIdx.x] = ws[0] + ws[1] + ws[2] + ws[3];
}

__global__ void k_bscan(int* __restrict__ bsum, int nb) { // in-place -> exclusive
  const int lane = threadIdx.x; // blockDim = 64
  int carry = 0;
  for (int base = 0; base < nb; base += 64) {
    const int idx = base + lane;
    int v = (idx < nb) ? bsum[idx] : 0;
    int inc = v;
#pragma unroll
    for (int s = 1; s < 64; s <<= 1) { int t = __shfl_up(inc, s); if (lane >= s) inc += t; }
    if (idx < nb) bsum[idx] = inc - v + carry;
    carry += __shfl(inc, 63);
  }
}

__global__ void k_finalize(const int* __restrict__ deg, const int* __restrict__ bsum,
                           int* __restrict__ ptr, float* __restrict__ dis) {
  const int i = blockIdx.x * 256 + threadIdx.x;
  const int lane = threadIdx.x & 63, wid = threadIdx.x >> 6;
  const int d = (i < N_NODES) ? deg[i] : 0;
  int inc = d;
#pragma unroll
  for (int s = 1; s < 64; s <<= 1) { int t = __shfl_up(inc, s); if (lane >= s) inc += t; }
  __shared__ int ws[4];
  if (lane == 63) ws[wid] = inc;
  __syncthreads();
  int woff = bsum[blockIdx.x];
  for (int w = 0; w < wid; ++w) woff += ws[w];
  if (i < N_NODES) {
    ptr[i] = woff + inc - d;                       // exclusive start (scatter cursor)
    dis[i] = 1.0f / sqrtf((float)(d > 0 ? d : 1));
  }
}

// XCD-team scatter v3:
// teams 0-3 own user-node ranges and stream only edges [0, 2M) (user rows);
// teams 4-7 own item-node ranges and stream only edges [2M, 4M) (item rows).
// Streaming reads are non-temporal so each team's ~2MB ecol write region
// stays resident in its XCD L2 -> full-line writebacks.
__global__ void k_scatter(const int* __restrict__ rows, const int* __restrict__ cols,
                          int* __restrict__ ptr, int* __restrict__ ecol) {
  const int team = blockIdx.x & 7;
  const int tb   = blockIdx.x >> 3;
  const int nTb  = gridDim.x >> 3;
  const bool userTeam = team < 4;
  const int lo = userTeam ? team * (USER_COUNT / 4)
                          : USER_COUNT + (team - 4) * (ITEM_COUNT / 4);
  const int hi = lo + (userTeam ? USER_COUNT / 4 : ITEM_COUNT / 4);
  const int ebase = userTeam ? 0 : N_EDGES / 2;
  const int stride = nTb * blockDim.x;
  for (int e = tb * blockDim.x + threadIdx.x; e < N_EDGES / 2; e += stride) {
    const int idx = ebase + e;
    const int r = __builtin_nontemporal_load(rows + idx);
    if (r >= lo && r < hi) {
      const int c = __builtin_nontemporal_load(cols + idx);
      int pos = atomicAdd(&ptr[r], 1);
      ecol[pos] = c;
    }
  }
}

// One wave per output row. 4 edge-slot groups x 16 lanes x float4:
// 16 independent X-row gathers in flight per wave (MLP), tails predicated.
// ecol reads are non-temporal (pure stream, keep X hot in L2).
template <int NOISE>
__global__ __launch_bounds__(256) void k_spmm(const int* __restrict__ ptr,
                                              const int* __restrict__ ecol,
                                              const float* __restrict__ dis,
                                              const float* __restrict__ X,
                                              float* __restrict__ Y,
                                              uint32_t k0, uint32_t k1) {
  const int w = (blockIdx.x * blockDim.x + threadIdx.x) >> 6;
  const int lane = threadIdx.x & 63;
  if (w >= N_NODES) return;
  const int g   = lane >> 4;   // edge-slot group 0..3
  const int sub = lane & 15;   // dim block: dims [sub*4, sub*4+4)
  const int e1 = ptr[w];                  // end (cursor after scatter)
  const int e0 = (w > 0) ? ptr[w - 1] : 0;
  const float4* __restrict__ X4 = (const float4*)X;

  float ax = 0.f, ay = 0.f, az = 0.f, aq = 0.f;
  for (int j = e0 + g; j < e1; j += 16) {
    const int j1 = j + 4, j2 = j + 8, j3 = j + 12;
    const bool o1 = j1 < e1, o2 = j2 < e1, o3 = j3 < e1;
    const int c0 = __builtin_nontemporal_load(ecol + j);
    const int c1 = __builtin_nontemporal_load(ecol + (o1 ? j1 : j));
    const int c2 = __builtin_nontemporal_load(ecol + (o2 ? j2 : j));
    const int c3 = __builtin_nontemporal_load(ecol + (o3 ? j3 : j));
    const float d0 = dis[c0];
    const float d1 = o1 ? dis[c1] : 0.f;
    const float d2 = o2 ? dis[c2] : 0.f;
    const float d3 = o3 ? dis[c3] : 0.f;
    const float4 x0 = X4[c0 * 16 + sub];
    const float4 x1 = X4[c1 * 16 + sub];
    const float4 x2 = X4[c2 * 16 + sub];
    const float4 x3 = X4[c3 * 16 + sub];
    ax = fmaf(d0, x0.x, ax); ay = fmaf(d0, x0.y, ay);
    az = fmaf(d0, x0.z, az); aq = fmaf(d0, x0.w, aq);
    ax = fmaf(d1, x1.x, ax); ay = fmaf(d1, x1.y, ay);
    az = fmaf(d1, x1.z, az); aq = fmaf(d1, x1.w, aq);
    ax = fmaf(d2, x2.x, ax); ay = fmaf(d2, x2.y, ay);
    az = fmaf(d2, x2.z, az); aq = fmaf(d2, x2.w, aq);
    ax = fmaf(d3, x3.x, ax); ay = fmaf(d3, x3.y, ay);
    az = fmaf(d3, x3.z, az); aq = fmaf(d3, x3.w, aq);
  }
  // reduce across the 4 edge-slot groups (lane, lane^16, lane^32, lane^48)
  ax += __shfl_xor(ax, 16); ax += __shfl_xor(ax, 32);
  ay += __shfl_xor(ay, 16); ay += __shfl_xor(ay, 32);
  az += __shfl_xor(az, 16); az += __shfl_xor(az, 32);
  aq += __shfl_xor(aq, 16); aq += __shfl_xor(aq, 32);

  const float dw = dis[w];
  float v0 = ax * dw, v1 = ay * dw, v2 = az * dw, v3 = aq * dw;

  if (NOISE) {
    // one threefry per lane: this lane owns dim d = sub*4 + g
    uint32_t t0 = 0u, t1 = (uint32_t)(w * EMB + sub * 4 + g);
    threefry2x32(k0, k1, t0, t1);
    const uint32_t bits = t0 ^ t1;
    const float u = __uint_as_float((bits >> 9) | 0x3f800000u) - 1.0f;
    float ss = u * u;
#pragma unroll
    for (int s = 1; s < 64; s <<= 1) ss += __shfl_xor(ss, s);
    const float inv = 1.0f / fmaxf(sqrtf(ss), 1e-12f);
    // gather this lane's 4 dim-noises: dim sub*4+t lives at lane t*16+sub
    const float u0 = __shfl(u, sub);
    const float u1 = __shfl(u, 16 + sub);
    const float u2 = __shfl(u, 32 + sub);
    const float u3 = __shfl(u, 48 + sub);
    const float e = EPS_F * inv;
    v0 = fmaf(((v0 > 0.f) ? 1.f : ((v0 < 0.f) ? -1.f : 0.f)) * u0, e, v0);
    v1 = fmaf(((v1 > 0.f) ? 1.f : ((v1 < 0.f) ? -1.f : 0.f)) * u1, e, v1);
    v2 = fmaf(((v2 > 0.f) ? 1.f : ((v2 < 0.f) ? -1.f : 0.f)) * u2, e, v2);
    v3 = fmaf(((v3 > 0.f) ? 1.f : ((v3 < 0.f) ? -1.f : 0.f)) * u3, e, v3);
  }
  if (g == 0) {
    float4 r; r.x = v0; r.y = v1; r.z = v2; r.w = v3;
    ((float4*)Y)[w * 16 + sub] = r;
  }
}

// gather batch rows; optional second (cl) destination at scale 1
__global__ __launch_bounds__(256) void k_gather(const float* __restrict__ X,
                                                const int* __restrict__ users,
                                                const int* __restrict__ items,
                                                float* __restrict__ out_u,
                                                float* __restrict__ out_i,
                                                float* __restrict__ cl_u,
                                                float* __restrict__ cl_i,
                                                float scale, int init) {
  const int w = (blockIdx.x * blockDim.x + threadIdx.x) >> 6;
  const int lane = threadIdx.x & 63;
  if (w >= 2 * BATCH) return;
  int src; float* dst; float* dst2;
  if (w < BATCH) {
    src = users[w];               dst = out_u + w * EMB;
    dst2 = cl_u ? cl_u + w * EMB : nullptr;
  } else {
    int q = w - BATCH;
    src = USER_COUNT + items[q];  dst = out_i + q * EMB;
    dst2 = cl_i ? cl_i + q * EMB : nullptr;
  }
  float raw = X[src * EMB + lane];
  float v = raw * scale;
  dst[lane] = init ? v : (dst[lane] + v);
  if (dst2) dst2[lane] = raw;
}

extern "C" void kernel_launch(void* const* d_in, const int* in_sizes, int n_in,
                              void* d_out, int out_size, void* d_ws, size_t ws_size,
                              hipStream_t stream) {
  const float* user_emb = (const float*)d_in[0];
  const float* item_emb = (const float*)d_in[1];
  // d_in[2] = vals: unused, recomputed bit-identically from degrees
  const int* rows  = (const int*)d_in[3];
  const int* cols  = (const int*)d_in[4];
  const int* users = (const int*)d_in[5];
  const int* items = (const int*)d_in[6];

  float* X   = (float*)d_ws;                       // 9.6M f32
  float* Y   = X + (size_t)N_NODES * EMB;          // 9.6M f32
  int*   deg = (int*)(Y + (size_t)N_NODES * EMB);  // 150k
  int*   ptr = deg + N_NODES;                      // 150k
  float* dis = (float*)(ptr + N_NODES);            // 150k
  int*   ecol = (int*)(dis + N_NODES);             // 4M
  int*   bsum = ecol + N_EDGES;                    // 586

  float* out  = (float*)d_out;
  float* u_all = out;
  float* i_all = out + (size_t)BATCH * EMB;
  float* u_tr  = out + (size_t)2 * BATCH * EMB;
  float* i_tr  = out + (size_t)3 * BATCH * EMB;
  float* u_cl  = out + (size_t)4 * BATCH * EMB;
  float* i_cl  = out + (size_t)5 * BATCH * EMB;

  // ---- build CSR (per launch, deterministic work) ----
  k_zero<<<NB_SCAN, 256, 0, stream>>>(deg, N_NODES);
  k_hist<<<1024, 256, 0, stream>>>(rows, deg);
  k_bsum<<<NB_SCAN, 256, 0, stream>>>(deg, bsum);
  k_bscan<<<1, 64, 0, stream>>>(bsum, NB_SCAN);
  k_finalize<<<NB_SCAN, 256, 0, stream>>>(deg, bsum, ptr, dis);
  k_scatter<<<2048, 256, 0, stream>>>(rows, cols, ptr, ecol);

  // ---- ego0 = concat(user_emb, item_emb) ----
  hipMemcpyAsync(X, user_emb, sizeof(float) * (size_t)USER_COUNT * EMB,
                 hipMemcpyDeviceToDevice, stream);
  hipMemcpyAsync(X + (size_t)USER_COUNT * EMB, item_emb,
                 sizeof(float) * (size_t)ITEM_COUNT * EMB,
                 hipMemcpyDeviceToDevice, stream);

  const int spmm_grid = (N_NODES * EMB + 255) / 256; // 37500
  const int gat_grid  = (2 * BATCH * EMB + 255) / 256; // 2048

  // ---- phase 1: 3 clean layers, mean-gather into outputs 0,1 ----
  for (int l = 0; l < 3; ++l) {
    k_spmm<0><<<spmm_grid, 256, 0, stream>>>(ptr, ecol, dis, X, Y, 0u, 0u);
    k_gather<<<gat_grid, 256, 0, stream>>>(Y, users, items, u_all, i_all,
                                           nullptr, nullptr, 1.0f / 3.0f, l == 0);
    float* t = X; X = Y; Y = t;
  }

  // ---- phase 2: 3 noisy layers (noise fused into spmm epilogue) ----
  for (int k = 0; k < 3; ++k) {
    uint32_t f0 = 0u, f1 = (uint32_t)k;      // fold_in(key(42), k)
    threefry2x32(0u, 42u, f0, f1);
    k_spmm<1><<<spmm_grid, 256, 0, stream>>>(ptr, ecol, dis, X, Y, f0, f1);
    k_gather<<<gat_grid, 256, 0, stream>>>(Y, users, items, u_tr, i_tr,
                                           (k == 0) ? u_cl : nullptr,
                                           (k == 0) ? i_cl : nullptr,
                                           1.0f / 3.0f, k == 0);
    float* t = X; X = Y; Y = t;
  }
}

// Round 7
// 1106.017 us; speedup vs baseline: 1.0666x; 1.0666x over previous
//
#include <hip/hip_runtime.h>
#include <stdint.h>

#define USER_COUNT 100000
#define ITEM_COUNT 50000
#define N_NODES    150000
#define EMB        64
#define N_EDGES    4000000
#define BATCH      4096
#define EPS_F      0.2f
#define NB_SCAN    ((N_NODES + 255) / 256)   // 586

typedef int int4v __attribute__((ext_vector_type(4)));

// ---- JAX threefry-2x32 (20 rounds), bit-exact ----
__host__ __device__ inline void threefry2x32(uint32_t k0, uint32_t k1,
                                             uint32_t& x0, uint32_t& x1) {
  const uint32_t ks2 = k0 ^ k1 ^ 0x1BD11BDAu;
  x0 += k0; x1 += k1;
#define TF_ROT(r) { x0 += x1; x1 = (x1 << (r)) | (x1 >> (32 - (r))); x1 ^= x0; }
  TF_ROT(13) TF_ROT(15) TF_ROT(26) TF_ROT(6)
  x0 += k1;  x1 += ks2 + 1u;
  TF_ROT(17) TF_ROT(29) TF_ROT(16) TF_ROT(24)
  x0 += ks2; x1 += k0 + 2u;
  TF_ROT(13) TF_ROT(15) TF_ROT(26) TF_ROT(6)
  x0 += k0;  x1 += k1 + 3u;
  TF_ROT(17) TF_ROT(29) TF_ROT(16) TF_ROT(24)
  x0 += k1;  x1 += ks2 + 4u;
  TF_ROT(13) TF_ROT(15) TF_ROT(26) TF_ROT(6)
  x0 += ks2; x1 += k0 + 5u;
#undef TF_ROT
}

__global__ void k_zero(int* __restrict__ p, int n) {
  int i = blockIdx.x * blockDim.x + threadIdx.x;
  if (i < n) p[i] = 0;
}

__global__ void k_hist(const int* __restrict__ rows, int* __restrict__ deg) {
  const int4v* __restrict__ r4 = (const int4v*)rows;
  int stride = gridDim.x * blockDim.x;
  for (int e = blockIdx.x * blockDim.x + threadIdx.x; e < N_EDGES / 4; e += stride) {
    int4v r = __builtin_nontemporal_load(r4 + e);
    atomicAdd(&deg[r.x], 1); atomicAdd(&deg[r.y], 1);
    atomicAdd(&deg[r.z], 1); atomicAdd(&deg[r.w], 1);
  }
}

// ---- parallel scan over deg: bsum -> bscan -> finalize ----
__global__ void k_bsum(const int* __restrict__ deg, int* __restrict__ bsum) {
  const int i = blockIdx.x * 256 + threadIdx.x;
  const int lane = threadIdx.x & 63, wid = threadIdx.x >> 6;
  int d = (i < N_NODES) ? deg[i] : 0;
#pragma unroll
  for (int s = 32; s; s >>= 1) d += __shfl_down(d, s);
  __shared__ int ws[4];
  if (lane == 0) ws[wid] = d;
  __syncthreads();
  if (threadIdx.x == 0) bsum[blockIdx.x] = ws[0] + ws[1] + ws[2] + ws[3];
}

__global__ void k_bscan(int* __restrict__ bsum, int nb) { // in-place -> exclusive
  const int lane = threadIdx.x; // blockDim = 64
  int carry = 0;
  for (int base = 0; base < nb; base += 64) {
    const int idx = base + lane;
    int v = (idx < nb) ? bsum[idx] : 0;
    int inc = v;
#pragma unroll
    for (int s = 1; s < 64; s <<= 1) { int t = __shfl_up(inc, s); if (lane >= s) inc += t; }
    if (idx < nb) bsum[idx] = inc - v + carry;
    carry += __shfl(inc, 63);
  }
}

__global__ void k_finalize(const int* __restrict__ deg, const int* __restrict__ bsum,
                           int* __restrict__ ptr, float* __restrict__ dis) {
  const int i = blockIdx.x * 256 + threadIdx.x;
  const int lane = threadIdx.x & 63, wid = threadIdx.x >> 6;
  const int d = (i < N_NODES) ? deg[i] : 0;
  int inc = d;
#pragma unroll
  for (int s = 1; s < 64; s <<= 1) { int t = __shfl_up(inc, s); if (lane >= s) inc += t; }
  __shared__ int ws[4];
  if (lane == 63) ws[wid] = inc;
  __syncthreads();
  int woff = bsum[blockIdx.x];
  for (int w = 0; w < wid; ++w) woff += ws[w];
  if (i < N_NODES) {
    ptr[i] = woff + inc - d;                       // exclusive start (scatter cursor)
    dis[i] = 1.0f / sqrtf((float)(d > 0 ? d : 1));
  }
}

// XCD-team scatter: teams 0-3 own user-node ranges, stream edges [0,2M);
// teams 4-7 own item-node ranges, stream edges [2M,4M).
__global__ void k_scatter(const int* __restrict__ rows, const int* __restrict__ cols,
                          int* __restrict__ ptr, int* __restrict__ ecol) {
  const int team = blockIdx.x & 7;
  const int tb   = blockIdx.x >> 3;
  const int nTb  = gridDim.x >> 3;
  const bool userTeam = team < 4;
  const int lo = userTeam ? team * (USER_COUNT / 4)
                          : USER_COUNT + (team - 4) * (ITEM_COUNT / 4);
  const int hi = lo + (userTeam ? USER_COUNT / 4 : ITEM_COUNT / 4);
  const int ebase = userTeam ? 0 : N_EDGES / 2;
  const int stride = nTb * blockDim.x;
  for (int e = tb * blockDim.x + threadIdx.x; e < N_EDGES / 2; e += stride) {
    const int idx = ebase + e;
    const int r = __builtin_nontemporal_load(rows + idx);
    if (r >= lo && r < hi) {
      const int c = __builtin_nontemporal_load(cols + idx);
      int pos = atomicAdd(&ptr[r], 1);
      ecol[pos] = c;
    }
  }
}

// Z0 = dis * concat(user_emb, item_emb), float4-wide
__global__ __launch_bounds__(256) void k_init(const float* __restrict__ ue,
                                              const float* __restrict__ ie,
                                              const float* __restrict__ dis,
                                              float* __restrict__ Z) {
  const int idx = blockIdx.x * blockDim.x + threadIdx.x; // float4 index
  if (idx >= N_NODES * 16) return;
  float4 v = (idx < USER_COUNT * 16) ? ((const float4*)ue)[idx]
                                     : ((const float4*)ie)[idx - USER_COUNT * 16];
  const float d = dis[idx >> 4];
  v.x *= d; v.y *= d; v.z *= d; v.w *= d;
  ((float4*)Z)[idx] = v;
}

// One wave per output row, Z-iteration: acc = sum_{c in N(r)} Z[c] (pure gather-sum).
// 4 groups x 16 lanes x float4; each lane runs 8 edge-slots -> 32 independent
// Z-row gathers in flight per wave; rows with deg<=32 finish in ONE latency round.
template <int NOISE>
__global__ __launch_bounds__(256) void k_spmm(const int* __restrict__ ptr,
                                              const int* __restrict__ ecol,
                                              const float* __restrict__ dis,
                                              const float* __restrict__ Z,
                                              float* __restrict__ Zout,
                                              uint32_t k0, uint32_t k1) {
  const int w = (blockIdx.x * blockDim.x + threadIdx.x) >> 6;
  const int lane = threadIdx.x & 63;
  if (w >= N_NODES) return;
  const int g   = lane >> 4;   // edge-slot group 0..3
  const int sub = lane & 15;   // dim block: dims [sub*4, sub*4+4)
  const int e1 = ptr[w];                  // end (cursor after scatter)
  const int e0 = (w > 0) ? ptr[w - 1] : 0;
  const float4* __restrict__ Z4 = (const float4*)Z;

  float ax = 0.f, ay = 0.f, az = 0.f, aq = 0.f;
  for (int j = e0 + g; j < e1; j += 32) {
    int  cc[8];
    bool ok[8];
#pragma unroll
    for (int s = 0; s < 8; ++s) {
      const int js = j + 4 * s;
      ok[s] = js < e1;
      cc[s] = __builtin_nontemporal_load(ecol + (ok[s] ? js : j));
    }
    float4 xv[8];
#pragma unroll
    for (int s = 0; s < 8; ++s) xv[s] = Z4[cc[s] * 16 + sub];
#pragma unroll
    for (int s = 0; s < 8; ++s) {
      const float m = ok[s] ? 1.f : 0.f;
      ax = fmaf(m, xv[s].x, ax); ay = fmaf(m, xv[s].y, ay);
      az = fmaf(m, xv[s].z, az); aq = fmaf(m, xv[s].w, aq);
    }
  }
  // reduce across the 4 edge-slot groups
  ax += __shfl_xor(ax, 16); ax += __shfl_xor(ax, 32);
  ay += __shfl_xor(ay, 16); ay += __shfl_xor(ay, 32);
  az += __shfl_xor(az, 16); az += __shfl_xor(az, 32);
  aq += __shfl_xor(aq, 16); aq += __shfl_xor(aq, 32);

  const float dw = dis[w];
  float z0, z1, z2, z3;
  if (NOISE) {
    // ego = dw * acc; ego += sign(ego)*u*eps/||n||; Zout = dw * ego
    float v0 = dw * ax, v1 = dw * ay, v2 = dw * az, v3 = dw * aq;
    uint32_t t0 = 0u, t1 = (uint32_t)(w * EMB + sub * 4 + g);
    threefry2x32(k0, k1, t0, t1);
    const uint32_t bits = t0 ^ t1;
    const float u = __uint_as_float((bits >> 9) | 0x3f800000u) - 1.0f;
    float ss = u * u;
#pragma unroll
    for (int s = 1; s < 64; s <<= 1) ss += __shfl_xor(ss, s);
    const float inv = 1.0f / fmaxf(sqrtf(ss), 1e-12f);
    const float u0 = __shfl(u, sub);
    const float u1 = __shfl(u, 16 + sub);
    const float u2 = __shfl(u, 32 + sub);
    const float u3 = __shfl(u, 48 + sub);
    const float e = EPS_F * inv;
    v0 = fmaf(((v0 > 0.f) ? 1.f : ((v0 < 0.f) ? -1.f : 0.f)) * u0, e, v0);
    v1 = fmaf(((v1 > 0.f) ? 1.f : ((v1 < 0.f) ? -1.f : 0.f)) * u1, e, v1);
    v2 = fmaf(((v2 > 0.f) ? 1.f : ((v2 < 0.f) ? -1.f : 0.f)) * u2, e, v2);
    v3 = fmaf(((v3 > 0.f) ? 1.f : ((v3 < 0.f) ? -1.f : 0.f)) * u3, e, v3);
    z0 = dw * v0; z1 = dw * v1; z2 = dw * v2; z3 = dw * v3;
  } else {
    const float d2 = dw * dw;
    z0 = d2 * ax; z1 = d2 * ay; z2 = d2 * az; z3 = d2 * aq;
  }
  if (g == 0) {
    float4 r; r.x = z0; r.y = z1; r.z = z2; r.w = z3;
    ((float4*)Zout)[w * 16 + sub] = r;
  }
}

// gather batch rows from Z, recovering ego = Z * sqrt(max(deg,1));
// optional second (cl) destination at scale 1
__global__ __launch_bounds__(256) void k_gather(const float* __restrict__ Z,
                                                const int* __restrict__ deg,
                                                const int* __restrict__ users,
                                                const int* __restrict__ items,
                                                float* __restrict__ out_u,
                                                float* __restrict__ out_i,
                                                float* __restrict__ cl_u,
                                                float* __restrict__ cl_i,
                                                float scale, int init) {
  const int w = (blockIdx.x * blockDim.x + threadIdx.x) >> 6;
  const int lane = threadIdx.x & 63;
  if (w >= 2 * BATCH) return;
  int src; float* dst; float* dst2;
  if (w < BATCH) {
    src = users[w];               dst = out_u + w * EMB;
    dst2 = cl_u ? cl_u + w * EMB : nullptr;
  } else {
    int q = w - BATCH;
    src = USER_COUNT + items[q];  dst = out_i + q * EMB;
    dst2 = cl_i ? cl_i + q * EMB : nullptr;
  }
  const int d = deg[src];
  const float rdis = sqrtf((float)(d > 0 ? d : 1));
  float raw = Z[src * EMB + lane] * rdis;
  float v = raw * scale;
  dst[lane] = init ? v : (dst[lane] + v);
  if (dst2) dst2[lane] = raw;
}

extern "C" void kernel_launch(void* const* d_in, const int* in_sizes, int n_in,
                              void* d_out, int out_size, void* d_ws, size_t ws_size,
                              hipStream_t stream) {
  const float* user_emb = (const float*)d_in[0];
  const float* item_emb = (const float*)d_in[1];
  // d_in[2] = vals: unused, recomputed bit-identically from degrees
  const int* rows  = (const int*)d_in[3];
  const int* cols  = (const int*)d_in[4];
  const int* users = (const int*)d_in[5];
  const int* items = (const int*)d_in[6];

  float* X   = (float*)d_ws;                       // 9.6M f32 (Z ping)
  float* Y   = X + (size_t)N_NODES * EMB;          // 9.6M f32 (Z pong)
  int*   deg = (int*)(Y + (size_t)N_NODES * EMB);  // 150k
  int*   ptr = deg + N_NODES;                      // 150k
  float* dis = (float*)(ptr + N_NODES);            // 150k
  int*   ecol = (int*)(dis + N_NODES);             // 4M
  int*   bsum = ecol + N_EDGES;                    // 586

  float* out  = (float*)d_out;
  float* u_all = out;
  float* i_all = out + (size_t)BATCH * EMB;
  float* u_tr  = out + (size_t)2 * BATCH * EMB;
  float* i_tr  = out + (size_t)3 * BATCH * EMB;
  float* u_cl  = out + (size_t)4 * BATCH * EMB;
  float* i_cl  = out + (size_t)5 * BATCH * EMB;

  // ---- build CSR (per launch, deterministic work) ----
  k_zero<<<NB_SCAN, 256, 0, stream>>>(deg, N_NODES);
  k_hist<<<1024, 256, 0, stream>>>(rows, deg);
  k_bsum<<<NB_SCAN, 256, 0, stream>>>(deg, bsum);
  k_bscan<<<1, 64, 0, stream>>>(bsum, NB_SCAN);
  k_finalize<<<NB_SCAN, 256, 0, stream>>>(deg, bsum, ptr, dis);
  k_scatter<<<2048, 256, 0, stream>>>(rows, cols, ptr, ecol);

  // ---- Z0 = dis * concat(user_emb, item_emb) ----
  k_init<<<(N_NODES * 16 + 255) / 256, 256, 0, stream>>>(user_emb, item_emb, dis, X);

  const int spmm_grid = (N_NODES * EMB + 255) / 256; // 37500
  const int gat_grid  = (2 * BATCH * EMB + 255) / 256; // 2048

  // ---- phase 1: 3 clean layers, mean-gather into outputs 0,1 ----
  for (int l = 0; l < 3; ++l) {
    k_spmm<0><<<spmm_grid, 256, 0, stream>>>(ptr, ecol, dis, X, Y, 0u, 0u);
    k_gather<<<gat_grid, 256, 0, stream>>>(Y, deg, users, items, u_all, i_all,
                                           nullptr, nullptr, 1.0f / 3.0f, l == 0);
    float* t = X; X = Y; Y = t;
  }

  // ---- phase 2: 3 noisy layers (noise fused into spmm epilogue) ----
  for (int k = 0; k < 3; ++k) {
    uint32_t f0 = 0u, f1 = (uint32_t)k;      // fold_in(key(42), k)
    threefry2x32(0u, 42u, f0, f1);
    k_spmm<1><<<spmm_grid, 256, 0, stream>>>(ptr, ecol, dis, X, Y, f0, f1);
    k_gather<<<gat_grid, 256, 0, stream>>>(Y, deg, users, items, u_tr, i_tr,
                                           (k == 0) ? u_cl : nullptr,
                                           (k == 0) ? i_cl : nullptr,
                                           1.0f / 3.0f, k == 0);
    float* t = X; X = Y; Y = t;
  }
}